// Round 11
// baseline (1600.762 us; speedup 1.0000x reference)
//
#include <hip/hip_runtime.h>

// ---------------- CSR build ----------------

__global__ void degree_kernel(const int* __restrict__ ei, int* __restrict__ deg, int E) {
    int e = blockIdx.x * blockDim.x + threadIdx.x;
    if (e < E) {
        int dst = ei[E + e];
        atomicAdd(&deg[dst], 1);
    }
}

// ---- hierarchical exclusive scan of deg -> offs (+ invd) ----

__global__ __launch_bounds__(512) void block_sum_kernel(
    const int* __restrict__ deg, int* __restrict__ bsum, int n)
{
    __shared__ int s[512];
    int i = blockIdx.x * 512 + threadIdx.x;
    s[threadIdx.x] = (i < n) ? deg[i] : 0;
    __syncthreads();
#pragma unroll
    for (int off = 256; off > 0; off >>= 1) {
        if (threadIdx.x < off) s[threadIdx.x] += s[threadIdx.x + off];
        __syncthreads();
    }
    if (threadIdx.x == 0) bsum[blockIdx.x] = s[0];
}

__global__ __launch_bounds__(1024) void bsum_scan_kernel(int* __restrict__ bsum, int nb) {
    __shared__ int s[1024];
    int t = threadIdx.x;
    s[t] = (t < nb) ? bsum[t] : 0;
    __syncthreads();
    for (int off = 1; off < 1024; off <<= 1) {
        int v = 0;
        if (t >= off) v = s[t - off];
        __syncthreads();
        if (t >= off) s[t] += v;
        __syncthreads();
    }
    if (t < nb) bsum[t] = (t == 0) ? 0 : s[t - 1];
}

__global__ __launch_bounds__(512) void scan_write_kernel(
    const int* __restrict__ deg, const int* __restrict__ bsum,
    int* __restrict__ offs, float* __restrict__ invd, int n, int E)
{
    __shared__ int s[512];
    int t = threadIdx.x;
    int i = blockIdx.x * 512 + t;
    int d = (i < n) ? deg[i] : 0;
    s[t] = d;
    __syncthreads();
    for (int off = 1; off < 512; off <<= 1) {
        int v = 0;
        if (t >= off) v = s[t - off];
        __syncthreads();
        if (t >= off) s[t] += v;
        __syncthreads();
    }
    if (i < n) {
        offs[i] = bsum[blockIdx.x] + s[t] - d;   // exclusive prefix
        invd[i] = 1.0f / (float)(d > 0 ? d : 1);
    }
    if (blockIdx.x == 0 && t == 0) offs[n] = E;
}

__global__ void fill_kernel(const int* __restrict__ ei, const int* __restrict__ offs,
                            int* __restrict__ cursor, int* __restrict__ csr, int E) {
    int e = blockIdx.x * blockDim.x + threadIdx.x;
    if (e < E) {
        int src = ei[e];
        int dst = ei[E + e];
        int pos = atomicAdd(&cursor[dst], 1);
        csr[offs[dst] + pos] = src;
    }
}

// ---------------- mean aggregation: one wave per node ----------------

template <int D>
__global__ __launch_bounds__(256) void aggregate_kernel(
    const float* __restrict__ h, const int* __restrict__ offs,
    const int* __restrict__ csr, const float* __restrict__ invd,
    float* __restrict__ mean, int nN)
{
    int wid = blockIdx.x * 4 + (threadIdx.x >> 6);
    int lane = threadIdx.x & 63;
    if (wid >= nN) return;
    int o0 = offs[wid], o1 = offs[wid + 1];
    constexpr int C = D / 64;
    float acc[C];
#pragma unroll
    for (int c = 0; c < C; c++) acc[c] = 0.f;
    int j = o0;
    for (; j + 1 < o1; j += 2) {
        int s0 = csr[j], s1 = csr[j + 1];
        const float* r0 = h + (size_t)s0 * D;
        const float* r1 = h + (size_t)s1 * D;
#pragma unroll
        for (int c = 0; c < C; c++) acc[c] += r0[lane + 64 * c];
#pragma unroll
        for (int c = 0; c < C; c++) acc[c] += r1[lane + 64 * c];
    }
    if (j < o1) {
        const float* r0 = h + (size_t)csr[j] * D;
#pragma unroll
        for (int c = 0; c < C; c++) acc[c] += r0[lane + 64 * c];
    }
    float iv = invd[wid];
#pragma unroll
    for (int c = 0; c < C; c++) mean[(size_t)wid * D + lane + 64 * c] = acc[c] * iv;
}

// ---------------- fused dual GEMM + bias + ReLU (streaming, no LDS) ----------------
// Round-9 post-mortem: sched_barrier within a chunk was null -> the stall is
// PREFETCH DISTANCE, not batching: a chunk's loads issue ~64 cyc before use,
// exposing one full memory latency per chunk. Fix: cross-chunk register
// double-buffer (named A/B buffer sets, fully unrolled k-loop) so every load
// issues one full chunk (>=256 FMA cycles) before its first use.

__device__ inline void fma4(float4& a, float s, const float4& w) {
    a.x = fmaf(s, w.x, a.x);
    a.y = fmaf(s, w.y, a.y);
    a.z = fmaf(s, w.z, a.z);
    a.w = fmaf(s, w.w, a.w);
}

template <int K, int M, int R>
__global__ __launch_bounds__(256, 3) void gemm_relu_stream(
    const float* __restrict__ A1, const float* __restrict__ A2,
    const float* __restrict__ wl, const float* __restrict__ wr,
    const float* __restrict__ bias, float* __restrict__ out, int nN)
{
    constexpr int TXc = M / 4;            // threads per row-group
    constexpr int GROUPS = 256 / TXc;     // row-groups per block
    const int tid = threadIdx.x;
    const int cq = (tid % TXc) * 4;       // column base for this thread
    const int g = tid / TXc;
    const int n0 = (blockIdx.x * GROUPS + g) * R;
    if (n0 >= nN) return;                 // no barriers below: early-out safe

    const float4 bv = *(const float4*)(bias + cq);
    float4 acc[R];
#pragma unroll
    for (int rr = 0; rr < R; rr++) acc[rr] = bv;

    if (n0 + R <= nN) {
        // -------- fast path: register-pipelined, prefetch distance = 1 chunk ----
        const float* __restrict__ a1p = A1 + (size_t)n0 * K;
        const float* __restrict__ a2p = A2 + (size_t)n0 * K;
        const float* __restrict__ wlp = wl + cq;
        const float* __restrict__ wrp = wr + cq;

        float4 wlA[4], wrA[4], a1A[R], a2A[R];   // buffer set A
        float4 wlB[4], wrB[4], a1B[R], a2B[R];   // buffer set B

#define LOAD_CH(WL, WR, A1V, A2V, kk)                                     \
        _Pragma("unroll") for (int j = 0; j < 4; j++) {                   \
            WL[j] = *(const float4*)(wlp + (size_t)((kk) + j) * M);       \
            WR[j] = *(const float4*)(wrp + (size_t)((kk) + j) * M);       \
        }                                                                 \
        _Pragma("unroll") for (int rr = 0; rr < R; rr++) {                \
            A1V[rr] = *(const float4*)(a1p + (size_t)rr * K + (kk));      \
            A2V[rr] = *(const float4*)(a2p + (size_t)rr * K + (kk));      \
        }                                                                 \
        __builtin_amdgcn_sched_barrier(0);

#define FMA_CH(WL, WR, A1V, A2V)                                          \
        _Pragma("unroll") for (int rr = 0; rr < R; rr++) {                \
            fma4(acc[rr], A1V[rr].x, WL[0]);                              \
            fma4(acc[rr], A1V[rr].y, WL[1]);                              \
            fma4(acc[rr], A1V[rr].z, WL[2]);                              \
            fma4(acc[rr], A1V[rr].w, WL[3]);                              \
            fma4(acc[rr], A2V[rr].x, WR[0]);                              \
            fma4(acc[rr], A2V[rr].y, WR[1]);                              \
            fma4(acc[rr], A2V[rr].z, WR[2]);                              \
            fma4(acc[rr], A2V[rr].w, WR[3]);                              \
        }

        LOAD_CH(wlA, wrA, a1A, a2A, 0)
#pragma unroll
        for (int k = 0; k < K; k += 8) {
            LOAD_CH(wlB, wrB, a1B, a2B, k + 4)
            FMA_CH(wlA, wrA, a1A, a2A)
            if (k + 8 < K) {
                LOAD_CH(wlA, wrA, a1A, a2A, k + 8)
            }
            FMA_CH(wlB, wrB, a1B, a2B)
        }
#undef LOAD_CH
#undef FMA_CH

#pragma unroll
        for (int rr = 0; rr < R; rr++) {
            float4 v = acc[rr];
            v.x = fmaxf(v.x, 0.f); v.y = fmaxf(v.y, 0.f);
            v.z = fmaxf(v.z, 0.f); v.w = fmaxf(v.w, 0.f);
            *(float4*)(out + (size_t)(n0 + rr) * M + cq) = v;
        }
    } else {
        // -------- slow path: partial tile (rare) --------
        for (int k = 0; k < K; k += 4) {
            float4 wlv[4], wrv[4];
#pragma unroll
            for (int j = 0; j < 4; j++) {
                wlv[j] = *(const float4*)(wl + (size_t)(k + j) * M + cq);
                wrv[j] = *(const float4*)(wr + (size_t)(k + j) * M + cq);
            }
#pragma unroll
            for (int rr = 0; rr < R; rr++) {
                int n = n0 + rr;
                if (n < nN) {
                    float4 a1 = *(const float4*)(A1 + (size_t)n * K + k);
                    float4 a2 = *(const float4*)(A2 + (size_t)n * K + k);
                    fma4(acc[rr], a1.x, wlv[0]);
                    fma4(acc[rr], a1.y, wlv[1]);
                    fma4(acc[rr], a1.z, wlv[2]);
                    fma4(acc[rr], a1.w, wlv[3]);
                    fma4(acc[rr], a2.x, wrv[0]);
                    fma4(acc[rr], a2.y, wrv[1]);
                    fma4(acc[rr], a2.z, wrv[2]);
                    fma4(acc[rr], a2.w, wrv[3]);
                }
            }
        }
#pragma unroll
        for (int rr = 0; rr < R; rr++) {
            int n = n0 + rr;
            if (n < nN) {
                float4 v = acc[rr];
                v.x = fmaxf(v.x, 0.f); v.y = fmaxf(v.y, 0.f);
                v.z = fmaxf(v.z, 0.f); v.w = fmaxf(v.w, 0.f);
                *(float4*)(out + (size_t)n * M + cq) = v;
            }
        }
    }
}

// ---------------- classifier: [N,32] @ [32,2] + bc ----------------

__global__ void classifier_kernel(const float* __restrict__ h,
                                  const float* __restrict__ wc,
                                  const float* __restrict__ bc,
                                  float* __restrict__ out, int nN) {
    int n = blockIdx.x * blockDim.x + threadIdx.x;
    if (n >= nN) return;
    float a0 = bc[0], a1 = bc[1];
    const float* row = h + (size_t)n * 32;
#pragma unroll
    for (int k = 0; k < 32; k++) {
        float v = row[k];
        a0 = fmaf(v, wc[k * 2 + 0], a0);
        a1 = fmaf(v, wc[k * 2 + 1], a1);
    }
    out[n * 2 + 0] = a0;
    out[n * 2 + 1] = a1;
}

// ---------------- launch ----------------

extern "C" void kernel_launch(void* const* d_in, const int* in_sizes, int n_in,
                              void* d_out, int out_size, void* d_ws, size_t ws_size,
                              hipStream_t stream) {
    const float* x   = (const float*)d_in[0];
    const int*   ei  = (const int*)d_in[1];   // [2,E] int32
    const float* w1l = (const float*)d_in[2];
    const float* b1l = (const float*)d_in[3];
    const float* w1r = (const float*)d_in[4];
    const float* w2l = (const float*)d_in[5];
    const float* b2l = (const float*)d_in[6];
    const float* w2r = (const float*)d_in[7];
    const float* w3l = (const float*)d_in[8];
    const float* b3l = (const float*)d_in[9];
    const float* w3r = (const float*)d_in[10];
    const float* wc  = (const float*)d_in[11];
    const float* bc  = (const float*)d_in[12];
    float* out = (float*)d_out;

    const int N = in_sizes[0] / 128;
    const int E = in_sizes[1] / 2;
    const int NB = (N + 511) / 512;           // scan blocks (<=1024)

    char* p = (char*)d_ws;
    auto alloc = [&](size_t bytes) {
        char* r = p;
        p += (bytes + 511) & ~(size_t)511;
        return r;
    };
    int*   deg    = (int*)  alloc((size_t)N * 4);
    int*   offs   = (int*)  alloc(((size_t)N + 1) * 4);
    int*   cursor = (int*)  alloc((size_t)N * 4);
    float* invd   = (float*)alloc((size_t)N * 4);
    int*   bsum   = (int*)  alloc((size_t)NB * 4);
    int*   csr    = (int*)  alloc((size_t)E * 4);
    float* mean   = (float*)alloc((size_t)N * 128 * 4);
    float* h1     = (float*)alloc((size_t)N * 128 * 4);
    float* h2     = (float*)alloc((size_t)N * 64 * 4);
    float* h3     = (float*)alloc((size_t)N * 32 * 4);

    hipMemsetAsync(deg, 0, (size_t)N * 4, stream);
    hipMemsetAsync(cursor, 0, (size_t)N * 4, stream);

    int eb = (E + 255) / 256;
    degree_kernel<<<eb, 256, 0, stream>>>(ei, deg, E);
    block_sum_kernel<<<NB, 512, 0, stream>>>(deg, bsum, N);
    bsum_scan_kernel<<<1, 1024, 0, stream>>>(bsum, NB);
    scan_write_kernel<<<NB, 512, 0, stream>>>(deg, bsum, offs, invd, N, E);
    fill_kernel<<<eb, 256, 0, stream>>>(ei, offs, cursor, csr, E);

    int ab = (N + 3) / 4;

    // rows per block = (256/(M/4)) * R
    constexpr int R = 4;
    int g1 = (N + (256 / (128 / 4)) * R - 1) / ((256 / (128 / 4)) * R);   // 32 rows/blk
    int g2 = (N + (256 / (64 / 4)) * R - 1) / ((256 / (64 / 4)) * R);     // 64 rows/blk
    int g3 = (N + (256 / (32 / 4)) * R - 1) / ((256 / (32 / 4)) * R);     // 128 rows/blk

    aggregate_kernel<128><<<ab, 256, 0, stream>>>(x, offs, csr, invd, mean, N);
    gemm_relu_stream<128, 128, R><<<g1, 256, 0, stream>>>(mean, x, w1l, w1r, b1l, h1, N);

    aggregate_kernel<128><<<ab, 256, 0, stream>>>(h1, offs, csr, invd, mean, N);
    gemm_relu_stream<128, 64, R><<<g2, 256, 0, stream>>>(mean, h1, w2l, w2r, b2l, h2, N);

    aggregate_kernel<64><<<ab, 256, 0, stream>>>(h2, offs, csr, invd, mean, N);
    gemm_relu_stream<64, 32, R><<<g3, 256, 0, stream>>>(mean, h2, w3l, w3r, b3l, h3, N);

    classifier_kernel<<<(N + 255) / 256, 256, 0, stream>>>(h3, wc, bc, out, N);
}

// Round 12
// 772.639 us; speedup vs baseline: 2.0718x; 2.0718x over previous
//
#include <hip/hip_runtime.h>

// ---------------- CSR build ----------------

__global__ void degree_kernel(const int* __restrict__ ei, int* __restrict__ deg, int E) {
    int e = blockIdx.x * blockDim.x + threadIdx.x;
    if (e < E) {
        int dst = ei[E + e];
        atomicAdd(&deg[dst], 1);
    }
}

// ---- hierarchical exclusive scan of deg -> offs (+ invd) ----

__global__ __launch_bounds__(512) void block_sum_kernel(
    const int* __restrict__ deg, int* __restrict__ bsum, int n)
{
    __shared__ int s[512];
    int i = blockIdx.x * 512 + threadIdx.x;
    s[threadIdx.x] = (i < n) ? deg[i] : 0;
    __syncthreads();
#pragma unroll
    for (int off = 256; off > 0; off >>= 1) {
        if (threadIdx.x < off) s[threadIdx.x] += s[threadIdx.x + off];
        __syncthreads();
    }
    if (threadIdx.x == 0) bsum[blockIdx.x] = s[0];
}

__global__ __launch_bounds__(1024) void bsum_scan_kernel(int* __restrict__ bsum, int nb) {
    __shared__ int s[1024];
    int t = threadIdx.x;
    s[t] = (t < nb) ? bsum[t] : 0;
    __syncthreads();
    for (int off = 1; off < 1024; off <<= 1) {
        int v = 0;
        if (t >= off) v = s[t - off];
        __syncthreads();
        if (t >= off) s[t] += v;
        __syncthreads();
    }
    if (t < nb) bsum[t] = (t == 0) ? 0 : s[t - 1];
}

__global__ __launch_bounds__(512) void scan_write_kernel(
    const int* __restrict__ deg, const int* __restrict__ bsum,
    int* __restrict__ offs, float* __restrict__ invd, int n, int E)
{
    __shared__ int s[512];
    int t = threadIdx.x;
    int i = blockIdx.x * 512 + t;
    int d = (i < n) ? deg[i] : 0;
    s[t] = d;
    __syncthreads();
    for (int off = 1; off < 512; off <<= 1) {
        int v = 0;
        if (t >= off) v = s[t - off];
        __syncthreads();
        if (t >= off) s[t] += v;
        __syncthreads();
    }
    if (i < n) {
        offs[i] = bsum[blockIdx.x] + s[t] - d;   // exclusive prefix
        invd[i] = 1.0f / (float)(d > 0 ? d : 1);
    }
    if (blockIdx.x == 0 && t == 0) offs[n] = E;
}

__global__ void fill_kernel(const int* __restrict__ ei, const int* __restrict__ offs,
                            int* __restrict__ cursor, int* __restrict__ csr, int E) {
    int e = blockIdx.x * blockDim.x + threadIdx.x;
    if (e < E) {
        int src = ei[e];
        int dst = ei[E + e];
        int pos = atomicAdd(&cursor[dst], 1);
        csr[offs[dst] + pos] = src;
    }
}

// ---------------- mean aggregation: one wave per node ----------------

template <int D>
__global__ __launch_bounds__(256) void aggregate_kernel(
    const float* __restrict__ h, const int* __restrict__ offs,
    const int* __restrict__ csr, const float* __restrict__ invd,
    float* __restrict__ mean, int nN)
{
    int wid = blockIdx.x * 4 + (threadIdx.x >> 6);
    int lane = threadIdx.x & 63;
    if (wid >= nN) return;
    int o0 = offs[wid], o1 = offs[wid + 1];
    constexpr int C = D / 64;
    float acc[C];
#pragma unroll
    for (int c = 0; c < C; c++) acc[c] = 0.f;
    int j = o0;
    for (; j + 1 < o1; j += 2) {
        int s0 = csr[j], s1 = csr[j + 1];
        const float* r0 = h + (size_t)s0 * D;
        const float* r1 = h + (size_t)s1 * D;
#pragma unroll
        for (int c = 0; c < C; c++) acc[c] += r0[lane + 64 * c];
#pragma unroll
        for (int c = 0; c < C; c++) acc[c] += r1[lane + 64 * c];
    }
    if (j < o1) {
        const float* r0 = h + (size_t)csr[j] * D;
#pragma unroll
        for (int c = 0; c < C; c++) acc[c] += r0[lane + 64 * c];
    }
    float iv = invd[wid];
#pragma unroll
    for (int c = 0; c < C; c++) mean[(size_t)wid * D + lane + 64 * c] = acc[c] * iv;
}

// ---------------- fused dual GEMM + bias + ReLU, W staged in LDS ----------------
// Round-11 analysis: streaming kernel was L1-BW-bound on W re-reads
// (8KB/chunk/wave x 32 chunks x all waves = 3.2 GB L1 traffic vs 102 MB of A;
// 256 B/cyc demanded vs ~64 B/cyc L1 -> VALUBusy 25%). Fix: stage W in LDS
// once per k-half (NOT per chunk; A never goes to LDS). Accumulators persist
// in registers across the two k-halves. W-L1 traffic -> ~50 MB total.

__device__ inline void fma4(float4& a, float s, const float4& w) {
    a.x = fmaf(s, w.x, a.x);
    a.y = fmaf(s, w.y, a.y);
    a.z = fmaf(s, w.z, a.z);
    a.w = fmaf(s, w.w, a.w);
}

template <int K, int M, int R>
__global__ __launch_bounds__(1024, 2) void gemm_relu_ldsw(
    const float* __restrict__ A1, const float* __restrict__ A2,
    const float* __restrict__ wl, const float* __restrict__ wr,
    const float* __restrict__ bias, float* __restrict__ out, int nN)
{
    constexpr int KH = K / 2;             // k-half staged at a time
    constexpr int TXc = M / 4;            // threads per row-group
    constexpr int GROUPS = 1024 / TXc;
    constexpr int ROWS = GROUPS * R;      // rows per block
    constexpr int F4 = KH * M / 4;        // float4s per matrix half

    __shared__ float ws[2 * KH * M];      // [0..) = wl half, [KH*M..) = wr half

    const int tid = threadIdx.x;
    const int cq = (tid % TXc) * 4;
    const int g = tid / TXc;
    const int nbase = blockIdx.x * ROWS;
    const int n0 = nbase + g * R;
    const bool full = (nbase + ROWS <= nN);

    const float4 bv = *(const float4*)(bias + cq);
    float4 acc[R];
#pragma unroll
    for (int rr = 0; rr < R; rr++) acc[rr] = bv;

#pragma unroll
    for (int h = 0; h < 2; h++) {
        __syncthreads();                   // previous half's compute done
        // ---- stage W half: contiguous coalesced float4 copy ----
        const float4* wlg = (const float4*)(wl + (size_t)h * KH * M);
        const float4* wrg = (const float4*)(wr + (size_t)h * KH * M);
        float4* s0 = (float4*)ws;
        float4* s1 = (float4*)(ws + KH * M);
        for (int i = tid; i < F4; i += 1024) {
            s0[i] = wlg[i];
            s1[i] = wrg[i];
        }
        __syncthreads();

        const int kbase = h * KH;
        if (full) {
            const float* __restrict__ a1p = A1 + (size_t)n0 * K + kbase;
            const float* __restrict__ a2p = A2 + (size_t)n0 * K + kbase;
            for (int kk0 = 0; kk0 < KH; kk0 += 4) {
                float4 a1v[R], a2v[R];
#pragma unroll
                for (int rr = 0; rr < R; rr++) {
                    a1v[rr] = *(const float4*)(a1p + (size_t)rr * K + kk0);
                    a2v[rr] = *(const float4*)(a2p + (size_t)rr * K + kk0);
                }
                float4 wlv[4], wrv[4];
#pragma unroll
                for (int j = 0; j < 4; j++) {
                    wlv[j] = *(const float4*)(&ws[(kk0 + j) * M + cq]);
                    wrv[j] = *(const float4*)(&ws[KH * M + (kk0 + j) * M + cq]);
                }
#pragma unroll
                for (int rr = 0; rr < R; rr++) {
                    fma4(acc[rr], a1v[rr].x, wlv[0]);
                    fma4(acc[rr], a1v[rr].y, wlv[1]);
                    fma4(acc[rr], a1v[rr].z, wlv[2]);
                    fma4(acc[rr], a1v[rr].w, wlv[3]);
                    fma4(acc[rr], a2v[rr].x, wrv[0]);
                    fma4(acc[rr], a2v[rr].y, wrv[1]);
                    fma4(acc[rr], a2v[rr].z, wrv[2]);
                    fma4(acc[rr], a2v[rr].w, wrv[3]);
                }
            }
        } else {
            // tail block: per-row guards (rare)
            for (int kk0 = 0; kk0 < KH; kk0 += 4) {
                float4 wlv[4], wrv[4];
#pragma unroll
                for (int j = 0; j < 4; j++) {
                    wlv[j] = *(const float4*)(&ws[(kk0 + j) * M + cq]);
                    wrv[j] = *(const float4*)(&ws[KH * M + (kk0 + j) * M + cq]);
                }
#pragma unroll
                for (int rr = 0; rr < R; rr++) {
                    int n = n0 + rr;
                    if (n < nN) {
                        float4 a1 = *(const float4*)(A1 + (size_t)n * K + kbase + kk0);
                        float4 a2 = *(const float4*)(A2 + (size_t)n * K + kbase + kk0);
                        fma4(acc[rr], a1.x, wlv[0]);
                        fma4(acc[rr], a1.y, wlv[1]);
                        fma4(acc[rr], a1.z, wlv[2]);
                        fma4(acc[rr], a1.w, wlv[3]);
                        fma4(acc[rr], a2.x, wrv[0]);
                        fma4(acc[rr], a2.y, wrv[1]);
                        fma4(acc[rr], a2.z, wrv[2]);
                        fma4(acc[rr], a2.w, wrv[3]);
                    }
                }
            }
        }
    }

#pragma unroll
    for (int rr = 0; rr < R; rr++) {
        int n = n0 + rr;
        if (n < nN) {
            float4 v = acc[rr];
            v.x = fmaxf(v.x, 0.f); v.y = fmaxf(v.y, 0.f);
            v.z = fmaxf(v.z, 0.f); v.w = fmaxf(v.w, 0.f);
            *(float4*)(out + (size_t)n * M + cq) = v;
        }
    }
}

// ---------------- classifier: [N,32] @ [32,2] + bc ----------------

__global__ void classifier_kernel(const float* __restrict__ h,
                                  const float* __restrict__ wc,
                                  const float* __restrict__ bc,
                                  float* __restrict__ out, int nN) {
    int n = blockIdx.x * blockDim.x + threadIdx.x;
    if (n >= nN) return;
    float a0 = bc[0], a1 = bc[1];
    const float* row = h + (size_t)n * 32;
#pragma unroll
    for (int k = 0; k < 32; k++) {
        float v = row[k];
        a0 = fmaf(v, wc[k * 2 + 0], a0);
        a1 = fmaf(v, wc[k * 2 + 1], a1);
    }
    out[n * 2 + 0] = a0;
    out[n * 2 + 1] = a1;
}

// ---------------- launch ----------------

extern "C" void kernel_launch(void* const* d_in, const int* in_sizes, int n_in,
                              void* d_out, int out_size, void* d_ws, size_t ws_size,
                              hipStream_t stream) {
    const float* x   = (const float*)d_in[0];
    const int*   ei  = (const int*)d_in[1];   // [2,E] int32
    const float* w1l = (const float*)d_in[2];
    const float* b1l = (const float*)d_in[3];
    const float* w1r = (const float*)d_in[4];
    const float* w2l = (const float*)d_in[5];
    const float* b2l = (const float*)d_in[6];
    const float* w2r = (const float*)d_in[7];
    const float* w3l = (const float*)d_in[8];
    const float* b3l = (const float*)d_in[9];
    const float* w3r = (const float*)d_in[10];
    const float* wc  = (const float*)d_in[11];
    const float* bc  = (const float*)d_in[12];
    float* out = (float*)d_out;

    const int N = in_sizes[0] / 128;
    const int E = in_sizes[1] / 2;
    const int NB = (N + 511) / 512;           // scan blocks (<=1024)

    char* p = (char*)d_ws;
    auto alloc = [&](size_t bytes) {
        char* r = p;
        p += (bytes + 511) & ~(size_t)511;
        return r;
    };
    int*   deg    = (int*)  alloc((size_t)N * 4);
    int*   offs   = (int*)  alloc(((size_t)N + 1) * 4);
    int*   cursor = (int*)  alloc((size_t)N * 4);
    float* invd   = (float*)alloc((size_t)N * 4);
    int*   bsum   = (int*)  alloc((size_t)NB * 4);
    int*   csr    = (int*)  alloc((size_t)E * 4);
    float* mean   = (float*)alloc((size_t)N * 128 * 4);
    float* h1     = (float*)alloc((size_t)N * 128 * 4);
    float* h2     = (float*)alloc((size_t)N * 64 * 4);
    float* h3     = (float*)alloc((size_t)N * 32 * 4);

    hipMemsetAsync(deg, 0, (size_t)N * 4, stream);
    hipMemsetAsync(cursor, 0, (size_t)N * 4, stream);

    int eb = (E + 255) / 256;
    degree_kernel<<<eb, 256, 0, stream>>>(ei, deg, E);
    block_sum_kernel<<<NB, 512, 0, stream>>>(deg, bsum, N);
    bsum_scan_kernel<<<1, 1024, 0, stream>>>(bsum, NB);
    scan_write_kernel<<<NB, 512, 0, stream>>>(deg, bsum, offs, invd, N, E);
    fill_kernel<<<eb, 256, 0, stream>>>(ei, offs, cursor, csr, E);

    int ab = (N + 3) / 4;

    // rows per block = (1024/(M/4)) * R, R=4 -> 16384/M
    int g1 = (N + 16384 / 128 - 1) / (16384 / 128);   // 128 rows/blk
    int g2 = (N + 16384 / 64  - 1) / (16384 / 64);    // 256 rows/blk
    int g3 = (N + 16384 / 32  - 1) / (16384 / 32);    // 512 rows/blk

    aggregate_kernel<128><<<ab, 256, 0, stream>>>(x, offs, csr, invd, mean, N);
    gemm_relu_ldsw<128, 128, 4><<<g1, 1024, 0, stream>>>(mean, x, w1l, w1r, b1l, h1, N);

    aggregate_kernel<128><<<ab, 256, 0, stream>>>(h1, offs, csr, invd, mean, N);
    gemm_relu_ldsw<128, 64, 4><<<g2, 1024, 0, stream>>>(mean, h1, w2l, w2r, b2l, h2, N);

    aggregate_kernel<64><<<ab, 256, 0, stream>>>(h2, offs, csr, invd, mean, N);
    gemm_relu_ldsw<64, 32, 4><<<g3, 1024, 0, stream>>>(mean, h2, w3l, w3r, b3l, h3, N);

    classifier_kernel<<<(N + 255) / 256, 256, 0, stream>>>(h3, wc, bc, out, N);
}